// Round 1
// 30880.099 us; speedup vs baseline: 1.2755x; 1.2755x over previous
//
#include <hip/hip_runtime.h>
#include <hip/hip_bf16.h>

// Bidirectional 2-layer LSTM, T=1024 B=64 H=512. Inputs/outputs fp32, compute
// bf16 MFMA (see R4 notes). Persistent kernel: 256 WGs = 4 stages
// (L0F,L0B,L1F,L1B) x 64 WGs; each WG owns 8 h-cols (32 gate cols x K=1024
// bf16 = 64 KB LDS, XOR-swizzled). L1 elastically chases L0 via W=16 ring.
//
// R5: the old barrier was atomic fetch_add on g_ctrs[4] -- all four counters
// on ONE cacheline -> 256 contended RMWs/round serialized at the coherence
// point (~150ns each ~= the whole 38us round), plus ACQUIRE poll loads that
// emit buffer_inv per iteration (L2 thrash). Replaced with:
//  - per-WG flag slots, 64B apart (zero RMWs: one release STORE per WG/round)
//  - wave-parallel polling: lane l of wave 0 watches slot l, __all() ballot,
//    RELAXED loads, single __threadfence() after detection
//  - waits moved off the critical path: L1 does its h-half GEMM before the
//    producer wait; L0's back-pressure check sits after its whole GEMM
//    (it only gates the ring-slot writes).

typedef __hip_bfloat16 bf16;
typedef short bf16x8 __attribute__((ext_vector_type(8)));   // 8 bf16 = 4 VGPRs
typedef float f32x4 __attribute__((ext_vector_type(4)));

constexpr int T = 1024, B = 64, H = 512, G4 = 2048;
constexpr int W = 16;         // ring slots per direction
constexpr int NW = 64;        // WGs per stage
constexpr int FSTRIDE = 16;   // unsigneds between flag slots (64 B)
constexpr size_t OUT_ELEMS = (size_t)T * B * 1024;          // 67,108,864
constexpr size_t HID_OFF   = OUT_ELEMS;                     // hidden [4,64,512]
constexpr size_t CELL_OFF  = OUT_ELEMS + (size_t)4 * B * H; // cell   [4,64,512]

__device__ unsigned g_flags[4 * NW * FSTRIDE];  // per-WG round flags (16 KB)
__device__ bf16 g_ring [2 * W * B * H];  // L0 h rings (F,B) - 2 MB
__device__ bf16 g_ring2[2 * W * B * H];  // L1 h rings (F,B) - 2 MB

__global__ void init_ctrs() {
  const int i = blockIdx.x * blockDim.x + threadIdx.x;
  if (i < 4 * NW * FSTRIDE) g_flags[i] = 0;
}

__device__ __forceinline__ bf16x8 cvt8(const float* p) {
  const float4 u = *(const float4*)p;
  const float4 v = *(const float4*)(p + 4);
  union { bf16 h[8]; bf16x8 r; } o;
  o.h[0] = __float2bfloat16(u.x); o.h[1] = __float2bfloat16(u.y);
  o.h[2] = __float2bfloat16(u.z); o.h[3] = __float2bfloat16(u.w);
  o.h[4] = __float2bfloat16(v.x); o.h[5] = __float2bfloat16(v.y);
  o.h[6] = __float2bfloat16(v.z); o.h[7] = __float2bfloat16(v.w);
  return o.r;
}

// Wave 0 only (tid<64): lane l watches slot l until ALL slots >= tgt.
__device__ __forceinline__ void wave_poll(const unsigned* base, int lane,
                                          unsigned tgt) {
  const unsigned* p = base + lane * FSTRIDE;
  for (;;) {
    unsigned v = __hip_atomic_load(p, __ATOMIC_RELAXED,
                                   __HIP_MEMORY_SCOPE_AGENT);
    if (__all((int)(v >= tgt))) break;
    __builtin_amdgcn_s_sleep(1);
  }
}

__global__ void __launch_bounds__(256, 1)
lstm_bidir(const float* __restrict__ x,
           const float* Wxf, const float* bxf, const float* Whf, const float* bhf,
           const float* Wxb, const float* bxb, const float* Whb, const float* bhb,
           float* out)
{
  __shared__ bf16 Wl[32 * 1024];   // 64 KB: 32 gate-col rows x K=1024 (swizzled)

  const int tid   = threadIdx.x;
  const int bid   = blockIdx.x;
  const int stage = bid & 3;       // L0F,L0B,L1F,L1B
  const int wg    = bid >> 2;      // 0..63
  const int dir   = stage & 1;
  const int layer = stage >> 1;
  const int c0    = wg * 8;        // h-col base owned by this WG

  const float* Wx = dir ? Wxb : Wxf;
  const float* Wh = dir ? Whb : Whf;
  const float* bx = dir ? bxb : bxf;
  const float* bh = dir ? bhb : bhf;
  bf16* ring  = g_ring  + (size_t)dir * W * B * H;  // L0 h (also L1's x source)
  bf16* ring2 = g_ring2 + (size_t)dir * W * B * H;  // L1 h recurrence

  // ---- stage weight slice into LDS (fp32 -> bf16); row n = j*4+g
  // 16B block kb stored at physical block kb ^ (n&7)  (bank de-conflict)
  for (int c = tid; c < 32 * 128; c += 256) {
    const int n  = c >> 7;               // 0..31
    const int kb = c & 127;              // 16B-bf16 block in K
    const int ke = kb * 8;               // elem offset 0..1016
    const int j = n >> 2, g = n & 3;
    const size_t row = (size_t)layer * G4 + (size_t)g * H + (c0 + j);
    const float* src = (ke < H) ? (Wx + row * H + ke) : (Wh + row * H + (ke - H));
    bf16x8 wv = cvt8(src);
    *(bf16x8*)(Wl + n * 1024 + ((kb ^ (n & 7)) * 8)) = wv;
  }

  const int lane = tid & 63, wi = tid >> 6;   // 4 waves
  const int quad = lane >> 4, mr = lane & 15;
  const int g2 = wi & 1;          // wave's 16-col group
  const int mh = wi >> 1;         // wave's 32-row half
  const int nb = g2 * 16 + mr;    // gate col within WG (0..31)
  const int j  = nb >> 2, gg = nb & 3;        // h-col within WG, gate id
  const int sw = nb & 7;          // swizzle key for this lane's B row

  const size_t brow = (size_t)layer * G4 + (size_t)gg * H + (c0 + j);
  const float bias = bx[brow] + bh[brow];     // fp32

  __syncthreads();  // weights ready (intra-WG)

  float cst[2][4] = {};           // c-state rows mh*32+m*16+quad*4+rr, col j
  unsigned nrounds = 0;
  unsigned*       myflags   = g_flags + stage * NW * FSTRIDE;
  const unsigned* prodflags = g_flags + dir * NW * FSTRIDE;        // L1 <- L0
  const unsigned* consflags = g_flags + (2 + dir) * NW * FSTRIDE;  // L0 <- L1

  const int r0 = (stage < 2) ? 0 : 1;
  for (int r = r0; r < r0 + T; ++r) {
    int t;
    if (stage == 0)      t = r;
    else if (stage == 1) t = (T - 1) - r;
    else if (stage == 2) t = r - 1;
    else                 t = T - r;

    const bool first = dir ? (t == T - 1) : (t == 0);
    const bool last  = dir ? (t == 0) : (t == T - 1);

    const float* xf = nullptr;      // L0: fp32 x
    const bf16 *xsb = nullptr;      // L1: bf16 x (= L0 ring)
    const bf16 *hsrc; bf16* hdst_bf; float* hdst_f32 = nullptr;
    if (stage < 2) {
      xf      = x    + (size_t)t * B * H;
      hsrc    = ring + (size_t)((r - 1) & (W - 1)) * B * H;
      hdst_bf = ring + (size_t)(r & (W - 1)) * B * H;
    } else {
      xsb      = ring  + (size_t)((r - 1) & (W - 1)) * B * H;  // L0's h for step t
      hsrc     = ring2 + (size_t)((r - 1) & (W - 1)) * B * H;  // own h_{t-1}
      hdst_bf  = ring2 + (size_t)(r & (W - 1)) * B * H;
      hdst_f32 = out + (size_t)t * B * 1024 + (size_t)dir * H;
    }

    // ---- GEMM: C[64,32] = [x_t ; h_{t-1}] (K=1024) @ Wslice, fp32 accum
    f32x4 acc0 = {0.f, 0.f, 0.f, 0.f};
    f32x4 acc1 = {0.f, 0.f, 0.f, 0.f};
    const int arow = mh * 32 + mr;

    if (stage < 2) {
      #pragma unroll
      for (int kk = 0; kk < 16; ++kk) {   // x part (fp32 -> bf16): K 0..511
        const int blk = kk * 4 + quad;
        bf16x8 bfr = *(const bf16x8*)(Wl + nb * 1024 + ((blk ^ sw) * 8));
        const float* ap = xf + (size_t)arow * H + blk * 8;
        bf16x8 a0 = cvt8(ap);
        bf16x8 a1 = cvt8(ap + (size_t)16 * H);
        acc0 = __builtin_amdgcn_mfma_f32_16x16x32_bf16(a0, bfr, acc0, 0, 0, 0);
        acc1 = __builtin_amdgcn_mfma_f32_16x16x32_bf16(a1, bfr, acc1, 0, 0, 0);
      }
      if (!first) {
        #pragma unroll
        for (int kk = 0; kk < 16; ++kk) {   // h part (bf16): K 512..1023
          const int blk = 64 + kk * 4 + quad;
          bf16x8 bfr = *(const bf16x8*)(Wl + nb * 1024 + ((blk ^ sw) * 8));
          const bf16* ap = hsrc + (size_t)arow * H + (kk * 4 + quad) * 8;
          bf16x8 a0 = *(const bf16x8*)(ap);
          bf16x8 a1 = *(const bf16x8*)(ap + (size_t)16 * H);
          acc0 = __builtin_amdgcn_mfma_f32_16x16x32_bf16(a0, bfr, acc0, 0, 0, 0);
          acc1 = __builtin_amdgcn_mfma_f32_16x16x32_bf16(a1, bfr, acc1, 0, 0, 0);
        }
      }
      // back-pressure: consumer must have finished reading the slot we are
      // about to overwrite (only gates the ring WRITES below, so wait here,
      // fully hidden behind the GEMM). No data read -> no acquire fence.
      if (r >= W) {
        if (tid < 64) wave_poll(consflags, tid, (unsigned)(r - W + 1));
        __syncthreads();
      }
    } else {
      if (!first) {
        #pragma unroll
        for (int kk = 0; kk < 16; ++kk) {   // h part first (own ring2, already
          const int blk = 64 + kk * 4 + quad;  // guarded by last round's barrier)
          bf16x8 bfr = *(const bf16x8*)(Wl + nb * 1024 + ((blk ^ sw) * 8));
          const bf16* ap = hsrc + (size_t)arow * H + (kk * 4 + quad) * 8;
          bf16x8 a0 = *(const bf16x8*)(ap);
          bf16x8 a1 = *(const bf16x8*)(ap + (size_t)16 * H);
          acc0 = __builtin_amdgcn_mfma_f32_16x16x32_bf16(a0, bfr, acc0, 0, 0, 0);
          acc1 = __builtin_amdgcn_mfma_f32_16x16x32_bf16(a1, bfr, acc1, 0, 0, 0);
        }
      }
      // producer wait: every L0 WG must have published round r (slot r-1 full)
      if (tid < 64) {
        wave_poll(prodflags, tid, (unsigned)r);
        __threadfence();  // acquire before ring read
      }
      __syncthreads();
      #pragma unroll
      for (int kk = 0; kk < 16; ++kk) {   // x part (bf16 ring): K 0..511
        const int blk = kk * 4 + quad;
        bf16x8 bfr = *(const bf16x8*)(Wl + nb * 1024 + ((blk ^ sw) * 8));
        const bf16* ap = xsb + (size_t)arow * H + blk * 8;
        bf16x8 a0 = *(const bf16x8*)(ap);
        bf16x8 a1 = *(const bf16x8*)(ap + (size_t)16 * H);
        acc0 = __builtin_amdgcn_mfma_f32_16x16x32_bf16(a0, bfr, acc0, 0, 0, 0);
        acc1 = __builtin_amdgcn_mfma_f32_16x16x32_bf16(a1, bfr, acc1, 0, 0, 0);
      }
    }

    // ---- gates: lane holds gate gg of (row, col j); partners in lanes ^1^2^3
    #pragma unroll
    for (int m = 0; m < 2; ++m) {
      const f32x4 av = m ? acc1 : acc0;
      #pragma unroll
      for (int rr = 0; rr < 4; ++rr) {
        const float v  = av[rr] + bias;
        const float v1 = __shfl_xor(v, 1);
        const float v2 = __shfl_xor(v, 2);
        const float v3 = __shfl_xor(v, 3);
        float gi, gf, gc, go;
        if (gg == 0)      { gi = v;  gf = v1; gc = v2; go = v3; }
        else if (gg == 1) { gi = v1; gf = v;  gc = v3; go = v2; }
        else if (gg == 2) { gi = v2; gf = v3; gc = v;  go = v1; }
        else              { gi = v3; gf = v2; gc = v1; go = v;  }
        const float si = 1.f / (1.f + __expf(-gi));
        const float sf = 1.f / (1.f + __expf(-gf));
        const float so = 1.f / (1.f + __expf(-go));
        const float tc = 1.f - 2.f / (1.f + __expf(2.f * gc));   // tanh, sat-safe
        const float c2 = sf * cst[m][rr] + si * tc;
        cst[m][rr] = c2;
        const float th = 1.f - 2.f / (1.f + __expf(2.f * c2));
        const float hv = so * th;
        if (gg == 0) {
          const int b = mh * 32 + m * 16 + quad * 4 + rr;
          hdst_bf[(size_t)b * H + (c0 + j)] = (bf16)hv;
          if (stage >= 2) hdst_f32[(size_t)b * 1024 + (c0 + j)] = hv;
          if (last) {
            const size_t p = (size_t)(dir * 2 + layer) * (B * H) + (size_t)b * H + (c0 + j);
            out[HID_OFF + p]  = hv;
            out[CELL_OFF + p] = c2;
          }
        }
      }
    }

    // ---- end-of-round stage barrier: publish flag (release), wave-parallel
    // poll of all 64 sibling flags, then one acquire fence.
    __syncthreads();   // all waves' ring stores drained (waitcnt before barrier)
    ++nrounds;
    if (tid < 64) {
      if (tid == 0) {
        __threadfence();  // release: this WG's h stores visible device-wide
        __hip_atomic_store(myflags + wg * FSTRIDE, nrounds,
                           __ATOMIC_RELEASE, __HIP_MEMORY_SCOPE_AGENT);
      }
      wave_poll(myflags, tid, nrounds);
      __threadfence();    // acquire: siblings' h visible next round
    }
    __syncthreads();
  }
}

extern "C" void kernel_launch(void* const* d_in, const int* in_sizes, int n_in,
                              void* d_out, int out_size, void* d_ws, size_t ws_size,
                              hipStream_t stream) {
  const float* x   = (const float*)d_in[0];
  const float* Wxf = (const float*)d_in[1];
  const float* bxf = (const float*)d_in[2];
  const float* Whf = (const float*)d_in[3];
  const float* bhf = (const float*)d_in[4];
  const float* Wxb = (const float*)d_in[5];
  const float* bxb = (const float*)d_in[6];
  const float* Whb = (const float*)d_in[7];
  const float* bhb = (const float*)d_in[8];
  float* out = (float*)d_out;

  hipLaunchKernelGGL(init_ctrs, dim3(16), dim3(256), 0, stream);
  hipLaunchKernelGGL(lstm_bidir, dim3(256), dim3(256), 0, stream,
                     x, Wxf, bxf, Whf, bhf, Wxb, bxb, Whb, bhb, out);
}

// Round 2
// 19496.387 us; speedup vs baseline: 2.0203x; 1.5839x over previous
//
#include <hip/hip_runtime.h>
#include <hip/hip_bf16.h>

// Bidirectional 2-layer LSTM, T=1024 B=64 H=512. Inputs/outputs fp32, compute
// bf16 MFMA. Persistent kernel: 256 WGs = 4 stages (L0F,L0B,L1F,L1B) x 64 WGs;
// each WG owns 8 h-cols (32 gate cols x K=1024 bf16 = 64 KB LDS, XOR-swizzled).
// L1 elastically chases L0 via W=16 ring.
//
// R5 removed atomic-RMW barrier contention (flags + wave-parallel poll).
// R6: remove ALL __threadfence() from the loop. The fences compiled to
// buffer_wbl2/buffer_inv sc1 -- whole-L2 writeback/invalidate scans, ~3 per WG
// per round, ~100 serialized L2 cache-ops per XCD per round ~= the entire
// 28us residual. Instead the ring data itself is made device-coherent:
//  - ring h stores: relaxed AGENT-scope atomic stores (global_store_short
//    sc0 sc1, write-through to coherence point). The vmcnt(0) implied before
//    s_barrier drains them; flag publish is a relaxed agent store after it.
//  - ring loads: relaxed AGENT-scope 8B atomic loads (global_load_dwordx2
//    sc0 sc1, bypass stale local L1/L2). Compiler-scheduled, pipelined.
//  - x (read-only) and out (read only at kernel end) stay ordinary.

typedef __hip_bfloat16 bf16;
typedef short bf16x8 __attribute__((ext_vector_type(8)));   // 8 bf16 = 4 VGPRs
typedef float f32x4 __attribute__((ext_vector_type(4)));
typedef unsigned long long u64;

constexpr int T = 1024, B = 64, H = 512, G4 = 2048;
constexpr int W = 16;         // ring slots per direction
constexpr int NW = 64;        // WGs per stage
constexpr int FSTRIDE = 16;   // unsigneds between flag slots (64 B)
constexpr size_t OUT_ELEMS = (size_t)T * B * 1024;          // 67,108,864
constexpr size_t HID_OFF   = OUT_ELEMS;                     // hidden [4,64,512]
constexpr size_t CELL_OFF  = OUT_ELEMS + (size_t)4 * B * H; // cell   [4,64,512]

__device__ __align__(256) unsigned g_flags[4 * NW * FSTRIDE]; // per-WG flags
__device__ __align__(256) bf16 g_ring [2 * W * B * H];  // L0 h rings (F,B) 2MB
__device__ __align__(256) bf16 g_ring2[2 * W * B * H];  // L1 h rings (F,B) 2MB

__global__ void init_ctrs() {
  const int i = blockIdx.x * blockDim.x + threadIdx.x;
  if (i < 4 * NW * FSTRIDE) g_flags[i] = 0;
}

__device__ __forceinline__ bf16x8 cvt8(const float* p) {
  const float4 u = *(const float4*)p;
  const float4 v = *(const float4*)(p + 4);
  union { bf16 h[8]; bf16x8 r; } o;
  o.h[0] = __float2bfloat16(u.x); o.h[1] = __float2bfloat16(u.y);
  o.h[2] = __float2bfloat16(u.z); o.h[3] = __float2bfloat16(u.w);
  o.h[4] = __float2bfloat16(v.x); o.h[5] = __float2bfloat16(v.y);
  o.h[6] = __float2bfloat16(v.z); o.h[7] = __float2bfloat16(v.w);
  return o.r;
}

// 16B ring read as two 8B device-coherent (agent-scope) loads: bypasses the
// (possibly stale) local L1/L2, sources from the coherence point.
__device__ __forceinline__ bf16x8 ld16_dev(const bf16* p) {
  union { u64 u[2]; bf16x8 v; } r;
  r.u[0] = __hip_atomic_load((const u64*)p,     __ATOMIC_RELAXED,
                             __HIP_MEMORY_SCOPE_AGENT);
  r.u[1] = __hip_atomic_load((const u64*)p + 1, __ATOMIC_RELAXED,
                             __HIP_MEMORY_SCOPE_AGENT);
  return r.v;
}

// 2B ring write, device-coherent write-through (no fence needed later).
__device__ __forceinline__ void st2_dev(bf16* p, float x) {
  const bf16 h = (bf16)x;
  unsigned short u;
  __builtin_memcpy(&u, &h, 2);
  __hip_atomic_store((unsigned short*)p, u, __ATOMIC_RELAXED,
                     __HIP_MEMORY_SCOPE_AGENT);
}

// Wave 0 only (tid<64): lane l watches slot l until ALL slots >= tgt.
__device__ __forceinline__ void wave_poll(const unsigned* base, int lane,
                                          unsigned tgt) {
  const unsigned* p = base + lane * FSTRIDE;
  for (;;) {
    unsigned v = __hip_atomic_load(p, __ATOMIC_RELAXED,
                                   __HIP_MEMORY_SCOPE_AGENT);
    if (__all((int)(v >= tgt))) break;
    __builtin_amdgcn_s_sleep(1);
  }
}

__global__ void __launch_bounds__(256, 1)
lstm_bidir(const float* __restrict__ x,
           const float* Wxf, const float* bxf, const float* Whf, const float* bhf,
           const float* Wxb, const float* bxb, const float* Whb, const float* bhb,
           float* out)
{
  __shared__ bf16 Wl[32 * 1024];   // 64 KB: 32 gate-col rows x K=1024 (swizzled)

  const int tid   = threadIdx.x;
  const int bid   = blockIdx.x;
  const int stage = bid & 3;       // L0F,L0B,L1F,L1B
  const int wg    = bid >> 2;      // 0..63
  const int dir   = stage & 1;
  const int layer = stage >> 1;
  const int c0    = wg * 8;        // h-col base owned by this WG

  const float* Wx = dir ? Wxb : Wxf;
  const float* Wh = dir ? Whb : Whf;
  const float* bx = dir ? bxb : bxf;
  const float* bh = dir ? bhb : bhf;
  bf16* ring  = g_ring  + (size_t)dir * W * B * H;  // L0 h (also L1's x source)
  bf16* ring2 = g_ring2 + (size_t)dir * W * B * H;  // L1 h recurrence

  // ---- stage weight slice into LDS (fp32 -> bf16); row n = j*4+g
  // 16B block kb stored at physical block kb ^ (n&7)  (bank de-conflict)
  for (int c = tid; c < 32 * 128; c += 256) {
    const int n  = c >> 7;               // 0..31
    const int kb = c & 127;              // 16B-bf16 block in K
    const int ke = kb * 8;               // elem offset 0..1016
    const int j = n >> 2, g = n & 3;
    const size_t row = (size_t)layer * G4 + (size_t)g * H + (c0 + j);
    const float* src = (ke < H) ? (Wx + row * H + ke) : (Wh + row * H + (ke - H));
    bf16x8 wv = cvt8(src);
    *(bf16x8*)(Wl + n * 1024 + ((kb ^ (n & 7)) * 8)) = wv;
  }

  const int lane = tid & 63, wi = tid >> 6;   // 4 waves
  const int quad = lane >> 4, mr = lane & 15;
  const int g2 = wi & 1;          // wave's 16-col group
  const int mh = wi >> 1;         // wave's 32-row half
  const int nb = g2 * 16 + mr;    // gate col within WG (0..31)
  const int j  = nb >> 2, gg = nb & 3;        // h-col within WG, gate id
  const int sw = nb & 7;          // swizzle key for this lane's B row

  const size_t brow = (size_t)layer * G4 + (size_t)gg * H + (c0 + j);
  const float bias = bx[brow] + bh[brow];     // fp32

  __syncthreads();  // weights ready (intra-WG)

  float cst[2][4] = {};           // c-state rows mh*32+m*16+quad*4+rr, col j
  unsigned nrounds = 0;
  unsigned*       myflags   = g_flags + stage * NW * FSTRIDE;
  const unsigned* prodflags = g_flags + dir * NW * FSTRIDE;        // L1 <- L0
  const unsigned* consflags = g_flags + (2 + dir) * NW * FSTRIDE;  // L0 <- L1

  const int r0 = (stage < 2) ? 0 : 1;
  for (int r = r0; r < r0 + T; ++r) {
    int t;
    if (stage == 0)      t = r;
    else if (stage == 1) t = (T - 1) - r;
    else if (stage == 2) t = r - 1;
    else                 t = T - r;

    const bool first = dir ? (t == T - 1) : (t == 0);
    const bool last  = dir ? (t == 0) : (t == T - 1);

    const float* xf = nullptr;      // L0: fp32 x
    const bf16 *xsb = nullptr;      // L1: bf16 x (= L0 ring)
    const bf16 *hsrc; bf16* hdst_bf; float* hdst_f32 = nullptr;
    if (stage < 2) {
      xf      = x    + (size_t)t * B * H;
      hsrc    = ring + (size_t)((r - 1) & (W - 1)) * B * H;
      hdst_bf = ring + (size_t)(r & (W - 1)) * B * H;
    } else {
      xsb      = ring  + (size_t)((r - 1) & (W - 1)) * B * H;  // L0's h for step t
      hsrc     = ring2 + (size_t)((r - 1) & (W - 1)) * B * H;  // own h_{t-1}
      hdst_bf  = ring2 + (size_t)(r & (W - 1)) * B * H;
      hdst_f32 = out + (size_t)t * B * 1024 + (size_t)dir * H;
    }

    // ---- GEMM: C[64,32] = [x_t ; h_{t-1}] (K=1024) @ Wslice, fp32 accum
    f32x4 acc0 = {0.f, 0.f, 0.f, 0.f};
    f32x4 acc1 = {0.f, 0.f, 0.f, 0.f};
    const int arow = mh * 32 + mr;

    if (stage < 2) {
      #pragma unroll
      for (int kk = 0; kk < 16; ++kk) {   // x part (fp32 -> bf16): K 0..511
        const int blk = kk * 4 + quad;
        bf16x8 bfr = *(const bf16x8*)(Wl + nb * 1024 + ((blk ^ sw) * 8));
        const float* ap = xf + (size_t)arow * H + blk * 8;
        bf16x8 a0 = cvt8(ap);
        bf16x8 a1 = cvt8(ap + (size_t)16 * H);
        acc0 = __builtin_amdgcn_mfma_f32_16x16x32_bf16(a0, bfr, acc0, 0, 0, 0);
        acc1 = __builtin_amdgcn_mfma_f32_16x16x32_bf16(a1, bfr, acc1, 0, 0, 0);
      }
      if (!first) {
        #pragma unroll
        for (int kk = 0; kk < 16; ++kk) {   // h part (bf16 ring): K 512..1023
          const int blk = 64 + kk * 4 + quad;
          bf16x8 bfr = *(const bf16x8*)(Wl + nb * 1024 + ((blk ^ sw) * 8));
          const bf16* ap = hsrc + (size_t)arow * H + (kk * 4 + quad) * 8;
          bf16x8 a0 = ld16_dev(ap);
          bf16x8 a1 = ld16_dev(ap + (size_t)16 * H);
          acc0 = __builtin_amdgcn_mfma_f32_16x16x32_bf16(a0, bfr, acc0, 0, 0, 0);
          acc1 = __builtin_amdgcn_mfma_f32_16x16x32_bf16(a1, bfr, acc1, 0, 0, 0);
        }
      }
      // back-pressure: consumer must have finished reading the slot we are
      // about to overwrite (only gates the ring WRITES below, so wait here,
      // fully hidden behind the GEMM). No data read -> no fence.
      if (r >= W) {
        if (tid < 64) wave_poll(consflags, tid, (unsigned)(r - W + 1));
        __syncthreads();
      }
    } else {
      if (!first) {
        #pragma unroll
        for (int kk = 0; kk < 16; ++kk) {   // h part first (own ring2, already
          const int blk = 64 + kk * 4 + quad;  // guarded by last round's barrier)
          bf16x8 bfr = *(const bf16x8*)(Wl + nb * 1024 + ((blk ^ sw) * 8));
          const bf16* ap = hsrc + (size_t)arow * H + (kk * 4 + quad) * 8;
          bf16x8 a0 = ld16_dev(ap);
          bf16x8 a1 = ld16_dev(ap + (size_t)16 * H);
          acc0 = __builtin_amdgcn_mfma_f32_16x16x32_bf16(a0, bfr, acc0, 0, 0, 0);
          acc1 = __builtin_amdgcn_mfma_f32_16x16x32_bf16(a1, bfr, acc1, 0, 0, 0);
        }
      }
      // producer wait: every L0 WG must have published round r (slot r-1 full).
      // Ring reads below bypass local caches -> no acquire fence needed.
      if (tid < 64) wave_poll(prodflags, tid, (unsigned)r);
      __syncthreads();
      #pragma unroll
      for (int kk = 0; kk < 16; ++kk) {   // x part (bf16 ring): K 0..511
        const int blk = kk * 4 + quad;
        bf16x8 bfr = *(const bf16x8*)(Wl + nb * 1024 + ((blk ^ sw) * 8));
        const bf16* ap = xsb + (size_t)arow * H + blk * 8;
        bf16x8 a0 = ld16_dev(ap);
        bf16x8 a1 = ld16_dev(ap + (size_t)16 * H);
        acc0 = __builtin_amdgcn_mfma_f32_16x16x32_bf16(a0, bfr, acc0, 0, 0, 0);
        acc1 = __builtin_amdgcn_mfma_f32_16x16x32_bf16(a1, bfr, acc1, 0, 0, 0);
      }
    }

    // ---- gates: lane holds gate gg of (row, col j); partners in lanes ^1^2^3
    #pragma unroll
    for (int m = 0; m < 2; ++m) {
      const f32x4 av = m ? acc1 : acc0;
      #pragma unroll
      for (int rr = 0; rr < 4; ++rr) {
        const float v  = av[rr] + bias;
        const float v1 = __shfl_xor(v, 1);
        const float v2 = __shfl_xor(v, 2);
        const float v3 = __shfl_xor(v, 3);
        float gi, gf, gc, go;
        if (gg == 0)      { gi = v;  gf = v1; gc = v2; go = v3; }
        else if (gg == 1) { gi = v1; gf = v;  gc = v3; go = v2; }
        else if (gg == 2) { gi = v2; gf = v3; gc = v;  go = v1; }
        else              { gi = v3; gf = v2; gc = v1; go = v;  }
        const float si = 1.f / (1.f + __expf(-gi));
        const float sf = 1.f / (1.f + __expf(-gf));
        const float so = 1.f / (1.f + __expf(-go));
        const float tc = 1.f - 2.f / (1.f + __expf(2.f * gc));   // tanh, sat-safe
        const float c2 = sf * cst[m][rr] + si * tc;
        cst[m][rr] = c2;
        const float th = 1.f - 2.f / (1.f + __expf(2.f * c2));
        const float hv = so * th;
        if (gg == 0) {
          const int b = mh * 32 + m * 16 + quad * 4 + rr;
          st2_dev(hdst_bf + (size_t)b * H + (c0 + j), hv);   // write-through
          if (stage >= 2) hdst_f32[(size_t)b * 1024 + (c0 + j)] = hv;
          if (last) {
            const size_t p = (size_t)(dir * 2 + layer) * (B * H) + (size_t)b * H + (c0 + j);
            out[HID_OFF + p]  = hv;
            out[CELL_OFF + p] = c2;
          }
        }
      }
    }

    // ---- end-of-round stage barrier: per-wave vmcnt(0) drain (write-through
    // stores then globally visible) -> barrier -> publish flag -> wave-parallel
    // poll of all 64 sibling flags. NO cache-maintenance ops.
    asm volatile("s_waitcnt vmcnt(0)" ::: "memory");
    __syncthreads();   // all waves' ring stores drained & visible
    ++nrounds;
    if (tid < 64) {
      if (tid == 0) {
        __hip_atomic_store(myflags + wg * FSTRIDE, nrounds,
                           __ATOMIC_RELAXED, __HIP_MEMORY_SCOPE_AGENT);
      }
      wave_poll(myflags, tid, nrounds);
    }
    __syncthreads();
  }
}

extern "C" void kernel_launch(void* const* d_in, const int* in_sizes, int n_in,
                              void* d_out, int out_size, void* d_ws, size_t ws_size,
                              hipStream_t stream) {
  const float* x   = (const float*)d_in[0];
  const float* Wxf = (const float*)d_in[1];
  const float* bxf = (const float*)d_in[2];
  const float* Whf = (const float*)d_in[3];
  const float* bhf = (const float*)d_in[4];
  const float* Wxb = (const float*)d_in[5];
  const float* bxb = (const float*)d_in[6];
  const float* Whb = (const float*)d_in[7];
  const float* bhb = (const float*)d_in[8];
  float* out = (float*)d_out;

  hipLaunchKernelGGL(init_ctrs, dim3(16), dim3(256), 0, stream);
  hipLaunchKernelGGL(lstm_bidir, dim3(256), dim3(256), 0, stream,
                     x, Wxf, bxf, Whf, bhf, Wxb, bxb, Whb, bhb, out);
}

// Round 3
// 18923.799 us; speedup vs baseline: 2.0814x; 1.0303x over previous
//
#include <hip/hip_runtime.h>
#include <hip/hip_bf16.h>

// Bidirectional 2-layer LSTM, T=1024 B=64 H=512. Inputs/outputs fp32, compute
// bf16 MFMA. Persistent kernel: 256 WGs = 4 stages (L0F,L0B,L1F,L1B) x 64 WGs;
// each WG owns 8 h-cols (32 gate cols x K=1024 bf16 = 64 KB LDS, XOR-swizzled).
// L1 elastically chases L0 via W=16 ring.
//
// R5: flags + wave-parallel poll (no atomic RMW contention).
// R6: fence-free coherence (agent-scope write-through stores / cache-bypass
//     loads for ring data; no buffer_wbl2/inv in the loop).
// R7 (this): kill the poll storm + un-expose the barrier hops.
//  - Epoch aggregation: only WG0 of each stage scans the 64 per-WG flags
//    (wave-parallel); it publishes ONE epoch word. Everybody else polls a
//    single epoch address with a single lane. Coherent-fabric poll traffic
//    drops ~32x (16K loads/iter -> ~0.5K).
//  - Barrier off the critical path: no end-of-round wait. Publish flag, start
//    next round's x-part immediately (independent of siblings); sibling wait
//    sits just before the h-part, hidden under the x-part GEMM. L1: producer
//    poll (steady-state instant) -> x-part -> sibling wait (hidden) -> h-part.
//  - Post-loop final epoch publish (consumers' last-round targets).

typedef __hip_bfloat16 bf16;
typedef short bf16x8 __attribute__((ext_vector_type(8)));   // 8 bf16 = 4 VGPRs
typedef float f32x4 __attribute__((ext_vector_type(4)));
typedef unsigned long long u64;

constexpr int T = 1024, B = 64, H = 512, G4 = 2048;
constexpr int W = 16;         // ring slots per direction
constexpr int NW = 64;        // WGs per stage
constexpr int FSTRIDE = 16;   // unsigneds between flag slots (64 B)
constexpr int ESTRIDE = 16;   // unsigneds between epoch slots (64 B)
constexpr size_t OUT_ELEMS = (size_t)T * B * 1024;          // 67,108,864
constexpr size_t HID_OFF   = OUT_ELEMS;                     // hidden [4,64,512]
constexpr size_t CELL_OFF  = OUT_ELEMS + (size_t)4 * B * H; // cell   [4,64,512]

__device__ __align__(256) unsigned g_flags[4 * NW * FSTRIDE]; // per-WG flags
__device__ __align__(256) unsigned g_epoch[4 * ESTRIDE];      // per-stage epoch
__device__ __align__(256) bf16 g_ring [2 * W * B * H];  // L0 h rings (F,B) 2MB
__device__ __align__(256) bf16 g_ring2[2 * W * B * H];  // L1 h rings (F,B) 2MB

__global__ void init_ctrs() {
  const int i = blockIdx.x * blockDim.x + threadIdx.x;
  if (i < 4 * NW * FSTRIDE) g_flags[i] = 0;
  if (i < 4 * ESTRIDE)      g_epoch[i] = 0;
}

__device__ __forceinline__ bf16x8 cvt8(const float* p) {
  const float4 u = *(const float4*)p;
  const float4 v = *(const float4*)(p + 4);
  union { bf16 h[8]; bf16x8 r; } o;
  o.h[0] = __float2bfloat16(u.x); o.h[1] = __float2bfloat16(u.y);
  o.h[2] = __float2bfloat16(u.z); o.h[3] = __float2bfloat16(u.w);
  o.h[4] = __float2bfloat16(v.x); o.h[5] = __float2bfloat16(v.y);
  o.h[6] = __float2bfloat16(v.z); o.h[7] = __float2bfloat16(v.w);
  return o.r;
}

// 16B ring read as two 8B device-coherent (agent-scope) loads: bypasses the
// (possibly stale) local L1/L2, sources from the coherence point.
__device__ __forceinline__ bf16x8 ld16_dev(const bf16* p) {
  union { u64 u[2]; bf16x8 v; } r;
  r.u[0] = __hip_atomic_load((const u64*)p,     __ATOMIC_RELAXED,
                             __HIP_MEMORY_SCOPE_AGENT);
  r.u[1] = __hip_atomic_load((const u64*)p + 1, __ATOMIC_RELAXED,
                             __HIP_MEMORY_SCOPE_AGENT);
  return r.v;
}

// 2B ring write, device-coherent write-through (no fence needed later).
__device__ __forceinline__ void st2_dev(bf16* p, float x) {
  const bf16 h = (bf16)x;
  unsigned short u;
  __builtin_memcpy(&u, &h, 2);
  __hip_atomic_store((unsigned short*)p, u, __ATOMIC_RELAXED,
                     __HIP_MEMORY_SCOPE_AGENT);
}

// Wave-parallel (64 lanes): lane l watches slot l until ALL slots >= tgt.
__device__ __forceinline__ void wave_poll(const unsigned* base, int lane,
                                          unsigned tgt) {
  const unsigned* p = base + lane * FSTRIDE;
  for (;;) {
    unsigned v = __hip_atomic_load(p, __ATOMIC_RELAXED,
                                   __HIP_MEMORY_SCOPE_AGENT);
    if (__all((int)(v >= tgt))) break;
    __builtin_amdgcn_s_sleep(1);
  }
}

// Single-lane poll of one word.
__device__ __forceinline__ void poll_ge(const unsigned* p, unsigned tgt) {
  while (__hip_atomic_load(p, __ATOMIC_RELAXED,
                           __HIP_MEMORY_SCOPE_AGENT) < tgt)
    __builtin_amdgcn_s_sleep(1);
}

__global__ void __launch_bounds__(256, 1)
lstm_bidir(const float* __restrict__ x,
           const float* Wxf, const float* bxf, const float* Whf, const float* bhf,
           const float* Wxb, const float* bxb, const float* Whb, const float* bhb,
           float* out)
{
  __shared__ bf16 Wl[32 * 1024];   // 64 KB: 32 gate-col rows x K=1024 (swizzled)

  const int tid   = threadIdx.x;
  const int bid   = blockIdx.x;
  const int stage = bid & 3;       // L0F,L0B,L1F,L1B
  const int wg    = bid >> 2;      // 0..63
  const int dir   = stage & 1;
  const int layer = stage >> 1;
  const int c0    = wg * 8;        // h-col base owned by this WG

  const float* Wx = dir ? Wxb : Wxf;
  const float* Wh = dir ? Whb : Whf;
  const float* bx = dir ? bxb : bxf;
  const float* bh = dir ? bhb : bhf;
  bf16* ring  = g_ring  + (size_t)dir * W * B * H;  // L0 h (also L1's x source)
  bf16* ring2 = g_ring2 + (size_t)dir * W * B * H;  // L1 h recurrence

  // ---- stage weight slice into LDS (fp32 -> bf16); row n = j*4+g
  // 16B block kb stored at physical block kb ^ (n&7)  (bank de-conflict)
  for (int c = tid; c < 32 * 128; c += 256) {
    const int n  = c >> 7;               // 0..31
    const int kb = c & 127;              // 16B-bf16 block in K
    const int ke = kb * 8;               // elem offset 0..1016
    const int j = n >> 2, g = n & 3;
    const size_t row = (size_t)layer * G4 + (size_t)g * H + (c0 + j);
    const float* src = (ke < H) ? (Wx + row * H + ke) : (Wh + row * H + (ke - H));
    bf16x8 wv = cvt8(src);
    *(bf16x8*)(Wl + n * 1024 + ((kb ^ (n & 7)) * 8)) = wv;
  }

  const int lane = tid & 63, wi = tid >> 6;   // 4 waves
  const int quad = lane >> 4, mr = lane & 15;
  const int g2 = wi & 1;          // wave's 16-col group
  const int mh = wi >> 1;         // wave's 32-row half
  const int nb = g2 * 16 + mr;    // gate col within WG (0..31)
  const int j  = nb >> 2, gg = nb & 3;        // h-col within WG, gate id
  const int sw = nb & 7;          // swizzle key for this lane's B row

  const size_t brow = (size_t)layer * G4 + (size_t)gg * H + (c0 + j);
  const float bias = bx[brow] + bh[brow];     // fp32

  __syncthreads();  // weights ready (intra-WG)

  float cst[2][4] = {};           // c-state rows mh*32+m*16+quad*4+rr, col j
  unsigned nrounds = 0;           // rounds completed by this WG
  unsigned*       myflags   = g_flags + stage * NW * FSTRIDE;
  unsigned*       myepoch   = g_epoch + stage * ESTRIDE;
  const unsigned* prodepoch = g_epoch + dir * ESTRIDE;        // L1 <- L0
  const unsigned* consepoch = g_epoch + (2 + dir) * ESTRIDE;  // L0 <- L1

  const int r0 = (stage < 2) ? 0 : 1;
  for (int r = r0; r < r0 + T; ++r) {
    int t;
    if (stage == 0)      t = r;
    else if (stage == 1) t = (T - 1) - r;
    else if (stage == 2) t = r - 1;
    else                 t = T - r;

    const bool first = dir ? (t == T - 1) : (t == 0);
    const bool last  = dir ? (t == 0) : (t == T - 1);

    const float* xf = nullptr;      // L0: fp32 x
    const bf16 *xsb = nullptr;      // L1: bf16 x (= L0 ring)
    const bf16 *hsrc; bf16* hdst_bf; float* hdst_f32 = nullptr;
    if (stage < 2) {
      xf      = x    + (size_t)t * B * H;
      hsrc    = ring + (size_t)((r - 1) & (W - 1)) * B * H;
      hdst_bf = ring + (size_t)(r & (W - 1)) * B * H;
    } else {
      xsb      = ring  + (size_t)((r - 1) & (W - 1)) * B * H;  // L0's h for step t
      hsrc     = ring2 + (size_t)((r - 1) & (W - 1)) * B * H;  // own h_{t-1}
      hdst_bf  = ring2 + (size_t)(r & (W - 1)) * B * H;
      hdst_f32 = out + (size_t)t * B * 1024 + (size_t)dir * H;
    }

    // ---- GEMM: C[64,32] = [x_t ; h_{t-1}] (K=1024) @ Wslice, fp32 accum
    f32x4 acc0 = {0.f, 0.f, 0.f, 0.f};
    f32x4 acc1 = {0.f, 0.f, 0.f, 0.f};
    const int arow = mh * 32 + mr;

    if (stage < 2) {
      #pragma unroll
      for (int kk = 0; kk < 16; ++kk) {   // x part (fp32 -> bf16): K 0..511
        const int blk = kk * 4 + quad;
        bf16x8 bfr = *(const bf16x8*)(Wl + nb * 1024 + ((blk ^ sw) * 8));
        const float* ap = xf + (size_t)arow * H + blk * 8;
        bf16x8 a0 = cvt8(ap);
        bf16x8 a1 = cvt8(ap + (size_t)16 * H);
        acc0 = __builtin_amdgcn_mfma_f32_16x16x32_bf16(a0, bfr, acc0, 0, 0, 0);
        acc1 = __builtin_amdgcn_mfma_f32_16x16x32_bf16(a1, bfr, acc1, 0, 0, 0);
      }
      // ---- waits, hidden behind the x-part GEMM above:
      //  siblings done round r-1 (gates h-part reads) + L1 back-pressure
      //  (gates this round's ring writes).
      if (tid < 64) {
        if (wg == 0) {
          wave_poll(myflags, tid, nrounds);       // scan 64 flags (aggregator)
          if (tid == 0) {
            __hip_atomic_store(myepoch, nrounds, __ATOMIC_RELAXED,
                               __HIP_MEMORY_SCOPE_AGENT);
            if (r >= W) poll_ge(consepoch, (unsigned)(r - W + 1));
          }
        } else if (tid == 0) {
          poll_ge(myepoch, nrounds);              // single-word sibling wait
          if (r >= W) poll_ge(consepoch, (unsigned)(r - W + 1));
        }
      }
      __syncthreads();
      if (!first) {
        #pragma unroll
        for (int kk = 0; kk < 16; ++kk) {   // h part (bf16 ring): K 512..1023
          const int blk = 64 + kk * 4 + quad;
          bf16x8 bfr = *(const bf16x8*)(Wl + nb * 1024 + ((blk ^ sw) * 8));
          const bf16* ap = hsrc + (size_t)arow * H + (kk * 4 + quad) * 8;
          bf16x8 a0 = ld16_dev(ap);
          bf16x8 a1 = ld16_dev(ap + (size_t)16 * H);
          acc0 = __builtin_amdgcn_mfma_f32_16x16x32_bf16(a0, bfr, acc0, 0, 0, 0);
          acc1 = __builtin_amdgcn_mfma_f32_16x16x32_bf16(a1, bfr, acc1, 0, 0, 0);
        }
      }
    } else {
      // producer wait: every L0 WG published round r. Steady state: L0 runs
      // up to ~W ahead -> this poll is a single satisfied fabric load.
      if (tid == 0) poll_ge(prodepoch, (unsigned)r);
      __syncthreads();
      #pragma unroll
      for (int kk = 0; kk < 16; ++kk) {   // x part (bf16 ring): K 0..511
        const int blk = kk * 4 + quad;
        bf16x8 bfr = *(const bf16x8*)(Wl + nb * 1024 + ((blk ^ sw) * 8));
        const bf16* ap = xsb + (size_t)arow * H + blk * 8;
        bf16x8 a0 = ld16_dev(ap);
        bf16x8 a1 = ld16_dev(ap + (size_t)16 * H);
        acc0 = __builtin_amdgcn_mfma_f32_16x16x32_bf16(a0, bfr, acc0, 0, 0, 0);
        acc1 = __builtin_amdgcn_mfma_f32_16x16x32_bf16(a1, bfr, acc1, 0, 0, 0);
      }
      // sibling wait (gates h-part), hidden behind the x-part GEMM above.
      if (tid < 64) {
        if (wg == 0) {
          wave_poll(myflags, tid, nrounds);
          if (tid == 0)
            __hip_atomic_store(myepoch, nrounds, __ATOMIC_RELAXED,
                               __HIP_MEMORY_SCOPE_AGENT);
        } else if (tid == 0) {
          poll_ge(myepoch, nrounds);
        }
      }
      __syncthreads();
      if (!first) {
        #pragma unroll
        for (int kk = 0; kk < 16; ++kk) {   // h part (own ring2): K 512..1023
          const int blk = 64 + kk * 4 + quad;
          bf16x8 bfr = *(const bf16x8*)(Wl + nb * 1024 + ((blk ^ sw) * 8));
          const bf16* ap = hsrc + (size_t)arow * H + (kk * 4 + quad) * 8;
          bf16x8 a0 = ld16_dev(ap);
          bf16x8 a1 = ld16_dev(ap + (size_t)16 * H);
          acc0 = __builtin_amdgcn_mfma_f32_16x16x32_bf16(a0, bfr, acc0, 0, 0, 0);
          acc1 = __builtin_amdgcn_mfma_f32_16x16x32_bf16(a1, bfr, acc1, 0, 0, 0);
        }
      }
    }

    // ---- gates: lane holds gate gg of (row, col j); partners in lanes ^1^2^3
    #pragma unroll
    for (int m = 0; m < 2; ++m) {
      const f32x4 av = m ? acc1 : acc0;
      #pragma unroll
      for (int rr = 0; rr < 4; ++rr) {
        const float v  = av[rr] + bias;
        const float v1 = __shfl_xor(v, 1);
        const float v2 = __shfl_xor(v, 2);
        const float v3 = __shfl_xor(v, 3);
        float gi, gf, gc, go;
        if (gg == 0)      { gi = v;  gf = v1; gc = v2; go = v3; }
        else if (gg == 1) { gi = v1; gf = v;  gc = v3; go = v2; }
        else if (gg == 2) { gi = v2; gf = v3; gc = v;  go = v1; }
        else              { gi = v3; gf = v2; gc = v1; go = v;  }
        const float si = 1.f / (1.f + __expf(-gi));
        const float sf = 1.f / (1.f + __expf(-gf));
        const float so = 1.f / (1.f + __expf(-go));
        const float tc = 1.f - 2.f / (1.f + __expf(2.f * gc));   // tanh, sat-safe
        const float c2 = sf * cst[m][rr] + si * tc;
        cst[m][rr] = c2;
        const float th = 1.f - 2.f / (1.f + __expf(2.f * c2));
        const float hv = so * th;
        if (gg == 0) {
          const int b = mh * 32 + m * 16 + quad * 4 + rr;
          st2_dev(hdst_bf + (size_t)b * H + (c0 + j), hv);   // write-through
          if (stage >= 2) hdst_f32[(size_t)b * 1024 + (c0 + j)] = hv;
          if (last) {
            const size_t p = (size_t)(dir * 2 + layer) * (B * H) + (size_t)b * H + (c0 + j);
            out[HID_OFF + p]  = hv;
            out[CELL_OFF + p] = c2;
          }
        }
      }
    }

    // ---- end of round: drain write-through h stores, publish flag, GO.
    // No waiting here -- the sibling wait happens mid-next-round, hidden
    // behind the x-part GEMM.
    asm volatile("s_waitcnt vmcnt(0)" ::: "memory");
    __syncthreads();   // all 4 waves' ring stores drained & visible
    ++nrounds;
    if (tid == 0) {
      __hip_atomic_store(myflags + wg * FSTRIDE, nrounds,
                         __ATOMIC_RELAXED, __HIP_MEMORY_SCOPE_AGENT);
    }
  }

  // final epoch publish (consumers' last-round targets reference epoch == T)
  if (wg == 0 && tid < 64) {
    wave_poll(myflags, tid, (unsigned)T);
    if (tid == 0)
      __hip_atomic_store(myepoch, (unsigned)T, __ATOMIC_RELAXED,
                         __HIP_MEMORY_SCOPE_AGENT);
  }
}

extern "C" void kernel_launch(void* const* d_in, const int* in_sizes, int n_in,
                              void* d_out, int out_size, void* d_ws, size_t ws_size,
                              hipStream_t stream) {
  const float* x   = (const float*)d_in[0];
  const float* Wxf = (const float*)d_in[1];
  const float* bxf = (const float*)d_in[2];
  const float* Whf = (const float*)d_in[3];
  const float* bhf = (const float*)d_in[4];
  const float* Wxb = (const float*)d_in[5];
  const float* bxb = (const float*)d_in[6];
  const float* Whb = (const float*)d_in[7];
  const float* bhb = (const float*)d_in[8];
  float* out = (float*)d_out;

  hipLaunchKernelGGL(init_ctrs, dim3(16), dim3(256), 0, stream);
  hipLaunchKernelGGL(lstm_bidir, dim3(256), dim3(256), 0, stream,
                     x, Wxf, bxf, Whf, bhf, Wxb, bxb, Whb, bhb, out);
}